// Round 9
// baseline (206.897 us; speedup 1.0000x reference)
//
#include <hip/hip_runtime.h>
#include <hip/hip_fp16.h>

#define D      64
#define BSHIFT 9
#define BSIZE  512    // nodes per bucket
#define NBMAX  256    // supports N <= 131072
#define CAP    8192   // edge capacity per bucket (lambda ~6.1k, 26 sigma)
#define CHUNK  4096   // binA LDS sort chunk

typedef _Float16 h2 __attribute__((ext_vector_type(2)));
union UH2 { unsigned u; h2 h; };

__device__ __forceinline__ unsigned short f2h(float f) {
    __half h = __float2half_rn(f);
    return *reinterpret_cast<unsigned short*>(&h);
}
__device__ __forceinline__ h2 u2h(unsigned u) { UH2 t; t.u = u; return t.h; }
__device__ __forceinline__ unsigned h2u(h2 h) { UH2 t; t.h = h; return t.u; }

// ===========================================================================
// binA: per-block LDS counting sort into NB coarse buckets (dst AND src keys),
// then COALESCED copy-out of dense per-bucket runs. Grid=512 x 512 threads
// (R4 best: 194 µs. R3's grid=1024 halved copy-out run lengths -> regressed;
// 512 threads fixed the 18%-occupancy latency stall seen in R2.)
// ===========================================================================
__global__ void __launch_bounds__(512)
binA_kernel(const int* __restrict__ src, const int* __restrict__ dst,
            int* __restrict__ curD, int* __restrict__ curS,
            unsigned int* __restrict__ bufD,
            unsigned short* __restrict__ bufS, int n_edges) {
    __shared__ unsigned int   stD[CHUNK];
    __shared__ unsigned short stS[CHUNK];
    __shared__ unsigned char  stDB[CHUNK], stSB[CHUNK];
    __shared__ int histD[NBMAX], histS[NBMAX];
    __shared__ int offD[NBMAX], offS[NBMAX];
    __shared__ int bgD[NBMAX], bgS[NBMAX];
    __shared__ int wtD[4], wtS[4];

    int t = threadIdx.x;
    int per = (n_edges + gridDim.x - 1) / gridDim.x;
    int lo = blockIdx.x * per;
    int hi = min(lo + per, n_edges);

    for (int c0 = lo; c0 < hi; c0 += CHUNK) {
        int m = min(CHUNK, hi - c0);
        if (t < NBMAX) { histD[t] = 0; histS[t] = 0; }
        __syncthreads();
        for (int i = t; i < m; i += 512) {
            atomicAdd(&histD[dst[c0 + i] >> BSHIFT], 1);
            atomicAdd(&histS[src[c0 + i] >> BSHIFT], 1);
        }
        __syncthreads();
        int vD = 0, vS = 0, xD = 0, xS = 0;
        if (t < NBMAX) {                         // waves 0-3 only (uniform)
            vD = histD[t]; vS = histS[t];
            xD = vD; xS = vS;
            // wave-level inclusive scan (6 shfl steps, no barriers)
#pragma unroll
            for (int o = 1; o < 64; o <<= 1) {
                int yD = __shfl_up(xD, o, 64);
                int yS = __shfl_up(xS, o, 64);
                if ((t & 63) >= o) { xD += yD; xS += yS; }
            }
            if ((t & 63) == 63) { wtD[t >> 6] = xD; wtS[t >> 6] = xS; }
        }
        __syncthreads();
        if (t < NBMAX) {
            int baseD = 0, baseS = 0;
            for (int w = 0; w < (t >> 6); ++w) { baseD += wtD[w]; baseS += wtS[w]; }
            offD[t] = baseD + xD - vD;           // exclusive scan
            offS[t] = baseS + xS - vS;
            bgD[t] = vD ? atomicAdd(&curD[t], vD) : 0;
            bgS[t] = vS ? atomicAdd(&curS[t], vS) : 0;
        }
        __syncthreads();
        for (int i = t; i < m; i += 512) {       // LDS scatter (sorted)
            int s = src[c0 + i], d = dst[c0 + i];
            int bd = d >> BSHIFT;
            int p = atomicAdd(&offD[bd], 1);
            stD[p]  = (unsigned)s | ((unsigned)(d & (BSIZE - 1)) << 17);
            stDB[p] = (unsigned char)bd;
            int bs = s >> BSHIFT;
            int q = atomicAdd(&offS[bs], 1);
            stS[q]  = (unsigned short)(s & (BSIZE - 1));
            stSB[q] = (unsigned char)bs;
        }
        __syncthreads();
        for (int i = t; i < m; i += 512) {       // coalesced copy-out
            int bd = stDB[i];
            int lb = offD[bd] - histD[bd];       // excl base (off now = end)
            int gp = bgD[bd] + (i - lb);
            if (gp < CAP) bufD[(size_t)bd * CAP + gp] = stD[i];
            int bs = stSB[i];
            int lb2 = offS[bs] - histS[bs];
            int gq = bgS[bs] + (i - lb2);
            if (gq < CAP) bufS[(size_t)bs * CAP + gq] = stS[i];
        }
        __syncthreads();
    }
}

// ===========================================================================
// binBC: blocks [0,nb): counting-sort dst-bucket in LDS -> dense edge list
// (aliases bufD) + packed rpd = beg | (deg<<21).
// Blocks [nb, 5*nb): R7 split — each src bucket is handled by FOUR staging
// sub-blocks of 128 nodes (filtered histogram of the bucket's bufS), fixing
// the 392-blocks-on-256-CUs starvation of the feats->xp1 streaming pass.
// (R7: 188.1 µs, −6 vs R4.)
// ===========================================================================
__global__ void __launch_bounds__(512)
binBC_kernel(const unsigned int* __restrict__ bufD,
             unsigned int* __restrict__ edgeC,        // == bufD (alias)
             const unsigned short* __restrict__ bufS,
             const int* __restrict__ curD, const int* __restrict__ curS,
             unsigned int* __restrict__ rpd,
             float* __restrict__ norm_out,
             const float* __restrict__ feats,
             uint2* __restrict__ xp1,
             int n_nodes, int nb) {
    __shared__ int hist[BSIZE], off[BSIZE], cnt2[BSIZE];
    __shared__ int stage[CAP];
    __shared__ int wt[8];
    int b = blockIdx.x, t = threadIdx.x;

    if (b < nb) {
        hist[t] = 0;
        __syncthreads();
        int m = min(curD[b], CAP);
        for (int e = t; e < m; e += 512)
            atomicAdd(&hist[bufD[(size_t)b * CAP + e] >> 17], 1);
        __syncthreads();
        int v = hist[t];
        int x = v;
#pragma unroll
        for (int o = 1; o < 64; o <<= 1) {
            int y = __shfl_up(x, o, 64);
            if ((t & 63) >= o) x += y;
        }
        if ((t & 63) == 63) wt[t >> 6] = x;
        __syncthreads();
        int base = 0;
        for (int w = 0; w < (t >> 6); ++w) base += wt[w];
        int excl = base + x - v;
        off[t] = excl;
        cnt2[t] = 0;
        __syncthreads();
        for (int e = t; e < m; e += 512) {
            unsigned w = bufD[(size_t)b * CAP + e];
            int dl = w >> 17;
            int s  = (int)(w & 0x1FFFFu);
            int pos = off[dl] + atomicAdd(&cnt2[dl], 1);
            stage[pos] = s;
        }
        __syncthreads();
        for (int e = t; e < m; e += 512)
            edgeC[(size_t)b * CAP + e] = (unsigned)stage[e];
        int node = (b << BSHIFT) + t;
        if (node < n_nodes)
            rpd[node] = (unsigned)(b * CAP + excl) |
                        ((unsigned)min(v, 2047) << 21);
    } else {
        int bb  = b - nb;              // 0 .. 4*nb-1
        int b2  = bb >> 2;             // source bucket
        int sub = bb & 3;              // which 128-node sub-range
        int lo  = sub << 7;            // local-id range [lo, lo+128)
        int node0 = (b2 << BSHIFT) + lo;
        if (t < 128) hist[t] = 0;
        __syncthreads();
        int m = min(curS[b2], CAP);
        for (int e = t; e < m; e += 512) {
            int v = (int)bufS[(size_t)b2 * CAP + e];
            int l = v - lo;
            if ((unsigned)l < 128u) atomicAdd(&hist[l], 1);
        }
        __syncthreads();
        int node = node0 + t;
        if (t < 128 && node < n_nodes)
            norm_out[node] = rsqrtf(fmaxf((float)hist[t], 1.0f));
        // fused scale: xp1[row] = fp16(feats[row] * norm_out[row])
        int m2 = min(128, n_nodes - node0);
        for (int i = t; i < m2 * 16; i += 512) {
            int row = i >> 4, c = i & 15;
            float no = rsqrtf(fmaxf((float)hist[row], 1.0f));
            float4 vv = ((const float4*)feats)[(size_t)(node0 + row) * 16 + c];
            uint2 o;
            o.x = (unsigned)f2h(vv.x * no) | ((unsigned)f2h(vv.y * no) << 16);
            o.y = (unsigned)f2h(vv.z * no) | ((unsigned)f2h(vv.w * no) << 16);
            xp1[(size_t)(node0 + row) * 16 + c] = o;
        }
    }
}

// ===========================================================================
// Fused gather + GEMV, TWO rows per wave — R9: W IN LDS, VGPR <= 64.
// R5/R6/R8 triangulation: gatherw is TLP-bound, not schedule-bound.
// gather-alone @40 VGPR (8 waves/SIMD) = 31 µs; fused @~104 VGPR
// (4 waves/SIMD) = 58 µs. Moving wp[32] (32 VGPRs) to LDS (8KB, lane-
// consecutive 4B reads = free 2-way bank aliasing) + __launch_bounds__(256,8)
// forces the allocator under 64 VGPR -> 8 waves/SIMD. GEMV arithmetic is
// bit-identical (same values, same fdot2 order; only W's storage moved).
// Loop body is R7's (R8's manual pipelining regressed — reverted).
// ===========================================================================
template <bool RELU, bool SCALE_OUT, bool OUT_HALF>
__global__ void __launch_bounds__(256, 8)
gatherw_kernel(const unsigned int* __restrict__ xp,     // fp16 rows, 32 uints
               const unsigned int* __restrict__ rpd,
               const unsigned int* __restrict__ edgeC,
               const float* __restrict__ norm_out,
               const float* __restrict__ W,
               const float* __restrict__ bias,
               void* __restrict__ outv, int n_nodes) {
    __shared__ int eld[4][64];     // wave-private edge staging
    __shared__ h2  wl[32][64];     // W pairs: wl[p][lane]=(W[2p][l],W[2p+1][l])
    int lane   = threadIdx.x & 63;
    int wv     = threadIdx.x >> 6;
    int g      = lane >> 3, l8 = lane & 7;
    int half   = g >> 2;           // 0 -> row A, 1 -> row B
    int g4     = g & 3;            // group within my row (0..3)
    int base32 = lane & 32;
    int l32    = lane & 31;
    int wid  = (blockIdx.x * blockDim.x + threadIdx.x) >> 6;
    int nw   = (gridDim.x * blockDim.x) >> 6;

    // cooperative W -> LDS (values identical to the old per-lane wp[32])
    for (int i = threadIdx.x; i < 32 * 64; i += 256) {
        int p = i >> 6, l = i & 63;
        h2 h;
        h.x = (_Float16)W[(2 * p) * D + l];
        h.y = (_Float16)W[(2 * p + 1) * D + l];
        wl[p][l] = h;
    }
    __syncthreads();
    float bj = bias[lane];

    int npairs = (n_nodes + 1) >> 1;
    for (int pr = wid; pr < npairs; pr += nw) {
        int r0 = pr * 2;
        int rme = r0 + half;                    // row this half-wave gathers
        unsigned pk = (rme < n_nodes) ? rpd[rme] : 0u;
        int begme = (int)(pk & 0x1FFFFFu);
        int degme = (int)(pk >> 21);
        const unsigned int* el = edgeC + begme;

        int dmax = min(degme, 32);
        // one coalesced load per half; staged in LDS while fully converged
        eld[wv][lane] = (l32 < dmax) ? (int)el[l32] : 0;

        h2 a0 = (h2)0, a1 = (h2)0, a2 = (h2)0, a3 = (h2)0;
        int e = g4;
        for (; e + 4 < dmax; e += 8) {
            int s0 = eld[wv][base32 + e];
            int s1 = eld[wv][base32 + e + 4];
            uint4 u = *(const uint4*)(xp + (size_t)s0 * 32 + l8 * 4);
            uint4 v = *(const uint4*)(xp + (size_t)s1 * 32 + l8 * 4);
            a0 += u2h(u.x); a1 += u2h(u.y); a2 += u2h(u.z); a3 += u2h(u.w);
            a0 += u2h(v.x); a1 += u2h(v.y); a2 += u2h(v.z); a3 += u2h(v.w);
        }
        for (; e < dmax; e += 4) {
            int s0 = eld[wv][base32 + e];
            uint4 u = *(const uint4*)(xp + (size_t)s0 * 32 + l8 * 4);
            a0 += u2h(u.x); a1 += u2h(u.y); a2 += u2h(u.z); a3 += u2h(u.w);
        }
        for (int e2 = 32 + g4; e2 < degme; e2 += 4) {   // rare deg>32 tail
            int s0 = (int)el[e2];
            uint4 u = *(const uint4*)(xp + (size_t)s0 * 32 + l8 * 4);
            a0 += u2h(u.x); a1 += u2h(u.y); a2 += u2h(u.z); a3 += u2h(u.w);
        }
        // reduce the 4 groups of each half (lane bits 3,4) — both rows at once
#pragma unroll
        for (int off = 8; off < 32; off <<= 1) {
            a0 += u2h(__shfl_xor(h2u(a0), off, 64));
            a1 += u2h(__shfl_xor(h2u(a1), off, 64));
            a2 += u2h(__shfl_xor(h2u(a2), off, 64));
            a3 += u2h(__shfl_xor(h2u(a3), off, 64));
        }
        // row A slice sums in lanes 0-7, row B in lanes 32-39
        unsigned au[4] = {h2u(a0), h2u(a1), h2u(a2), h2u(a3)};

        // dual GEMV: pair p of row A in lane p>>2, row B in lane 32+(p>>2)
        float accA = 0.0f, accB = 0.0f;
#pragma unroll
        for (int p = 0; p < 32; ++p) {
            UH2 ta, tb;
            ta.u = __builtin_amdgcn_readlane(au[p & 3], p >> 2);
            tb.u = __builtin_amdgcn_readlane(au[p & 3], 32 + (p >> 2));
            h2 wpv = wl[p][lane];
            accA = __builtin_amdgcn_fdot2(ta.h, wpv, accA, false);
            accB = __builtin_amdgcn_fdot2(tb.h, wpv, accB, false);
        }

        int degA = __builtin_amdgcn_readlane(degme, 0);
        int degB = __builtin_amdgcn_readlane(degme, 32);
        {
            float ni = rsqrtf(fmaxf((float)degA, 1.0f));
            float o  = fmaf(accA, ni, bj);
            if (RELU) o = fmaxf(o, 0.0f);
            if (SCALE_OUT) o *= norm_out[r0];
            if (OUT_HALF)
                ((unsigned short*)outv)[(size_t)r0 * D + lane] = f2h(o);
            else
                ((float*)outv)[(size_t)r0 * D + lane] = o;
        }
        if (r0 + 1 < n_nodes) {
            float ni = rsqrtf(fmaxf((float)degB, 1.0f));
            float o  = fmaf(accB, ni, bj);
            if (RELU) o = fmaxf(o, 0.0f);
            if (SCALE_OUT) o *= norm_out[r0 + 1];
            if (OUT_HALF)
                ((unsigned short*)outv)[(size_t)(r0 + 1) * D + lane] = f2h(o);
            else
                ((float*)outv)[(size_t)(r0 + 1) * D + lane] = o;
        }
    }
}

// ===========================================================================
// Minimal fallback (R1 atomic path) — only if workspace is tiny
// ===========================================================================
__global__ void degree_kernel(const int* __restrict__ src,
                              const int* __restrict__ dst,
                              float* __restrict__ deg_out,
                              float* __restrict__ deg_in, int n_edges) {
    int e = blockIdx.x * blockDim.x + threadIdx.x;
    if (e < n_edges) {
        atomicAdd(&deg_out[src[e]], 1.0f);
        atomicAdd(&deg_in[dst[e]], 1.0f);
    }
}
__global__ void norm_kernel(float* __restrict__ deg, int n) {
    int i = blockIdx.x * blockDim.x + threadIdx.x;
    if (i < n) deg[i] = rsqrtf(fmaxf(deg[i], 1.0f));
}
__global__ void spmm_kernel(const float* __restrict__ x,
                            const int* __restrict__ src,
                            const int* __restrict__ dst,
                            const float* __restrict__ norm_out,
                            float* __restrict__ agg, int n_edges) {
    int gid = blockIdx.x * blockDim.x + threadIdx.x;
    int e = gid >> 6, lane = threadIdx.x & 63;
    if (e < n_edges) {
        int s = src[e], d = dst[e];
        atomicAdd(&agg[(size_t)d * D + lane],
                  x[(size_t)s * D + lane] * norm_out[s]);
    }
}
template <bool RELU>
__global__ void gemm_kernel(const float* __restrict__ agg,
                            const float* __restrict__ norm_in,
                            const float* __restrict__ W,
                            const float* __restrict__ b,
                            float* __restrict__ out, int n_nodes) {
    __shared__ float Wl[D * D];
    for (int i = threadIdx.x; i < D * D; i += blockDim.x) Wl[i] = W[i];
    __syncthreads();
    int lane = threadIdx.x & 63, wave = threadIdx.x >> 6;
    int wpb = blockDim.x >> 6;
    float bj = b[lane];
    for (int row = blockIdx.x * wpb + wave; row < n_nodes;
         row += gridDim.x * wpb) {
        float aa = agg[(size_t)row * D + lane] * norm_in[row];
        float acc = bj;
#pragma unroll
        for (int k = 0; k < D; ++k)
            acc = fmaf(__shfl(aa, k, 64), Wl[k * D + lane], acc);
        if (RELU) acc = fmaxf(acc, 0.0f);
        out[(size_t)row * D + lane] = acc;
    }
}

// ===========================================================================
// Launch
// ===========================================================================
extern "C" void kernel_launch(void* const* d_in, const int* in_sizes, int n_in,
                              void* d_out, int out_size, void* d_ws, size_t ws_size,
                              hipStream_t stream) {
    const float* feats = (const float*)d_in[0];
    const int*   src   = (const int*)  d_in[1];
    const int*   dst   = (const int*)  d_in[2];
    const float* W1    = (const float*)d_in[3];
    const float* b1    = (const float*)d_in[4];
    const float* W2    = (const float*)d_in[5];
    const float* b2    = (const float*)d_in[6];
    float*       out   = (float*)d_out;

    const int n_nodes = in_sizes[0] / D;   // 100000
    const int n_edges = in_sizes[1];       // 1200000
    const size_t nd = (size_t)n_nodes * D;
    const int nb = (n_nodes + BSIZE - 1) >> BSHIFT;

    // Layout: [bufD nb*CAP u32 (reused as edgeC)][bufS nb*CAP u16]
    //         [xp1 half N*D][xa half N*D][rpd N][norm_out N][curD 256][curS 256]
    size_t bufD_sz = (size_t)nb * CAP * 4;
    size_t bufS_sz = (size_t)nb * CAP * 2;
    size_t need = bufD_sz + bufS_sz + nd * 2 * 2 + (size_t)n_nodes * 8 + 2048;

    if (ws_size >= need && nb <= NBMAX && (size_t)nb * CAP < (1u << 21)) {
        char* base = (char*)d_ws;
        unsigned int*   bufD = (unsigned int*)base;
        unsigned short* bufS = (unsigned short*)(base + bufD_sz);
        unsigned int*   xp1  = (unsigned int*)(base + bufD_sz + bufS_sz);
        unsigned int*   xa   = (unsigned int*)((char*)xp1 + nd * 2);
        unsigned int*   rpd  = (unsigned int*)((char*)xa + nd * 2);
        float* norm_out = (float*)(rpd + n_nodes);
        int*   curD     = (int*)(norm_out + n_nodes);
        int*   curS     = curD + 256;

        hipMemsetAsync(curD, 0, 2048, stream);
        binA_kernel<<<512, 512, 0, stream>>>(src, dst, curD, curS, bufD, bufS,
                                             n_edges);
        binBC_kernel<<<5 * nb, 512, 0, stream>>>(bufD, bufD, bufS, curD, curS,
                                                 rpd, norm_out,
                                                 feats, (uint2*)xp1,
                                                 n_nodes, nb);

        // Layer 1: xp1 -> xa (fp16, pre-scaled by norm_out for next layer)
        gatherw_kernel<true, true, true><<<6400, 256, 0, stream>>>(
            xp1, rpd, bufD, norm_out, W1, b1, xa, n_nodes);
        // Layer 2: xa -> final fp32 out
        gatherw_kernel<false, false, false><<<6400, 256, 0, stream>>>(
            xa, rpd, bufD, norm_out, W2, b2, out, n_nodes);
        return;
    }

    // ---------------- fallback: R1 atomic path ----------------
    float* deg_out = (float*)d_ws;
    float* deg_in  = deg_out + n_nodes;
    float* agg     = deg_in + n_nodes;
    float* x       = out;

    hipMemsetAsync(d_ws, 0, (2 * (size_t)n_nodes + nd) * sizeof(float), stream);
    degree_kernel<<<(n_edges + 255) / 256, 256, 0, stream>>>(src, dst, deg_out,
                                                             deg_in, n_edges);
    norm_kernel<<<(2 * n_nodes + 255) / 256, 256, 0, stream>>>(deg_out,
                                                               2 * n_nodes);
    {
        long long threads = (long long)n_edges * 64;
        int blocks = (int)((threads + 255) / 256);
        spmm_kernel<<<blocks, 256, 0, stream>>>(feats, src, dst, deg_out, agg,
                                                n_edges);
    }
    gemm_kernel<true><<<(n_nodes + 3) / 4, 256, 0, stream>>>(agg, deg_in, W1,
                                                             b1, x, n_nodes);
    hipMemsetAsync(agg, 0, nd * sizeof(float), stream);
    {
        long long threads = (long long)n_edges * 64;
        int blocks = (int)((threads + 255) / 256);
        spmm_kernel<<<blocks, 256, 0, stream>>>(x, src, dst, deg_out, agg,
                                                n_edges);
    }
    gemm_kernel<false><<<(n_nodes + 3) / 4, 256, 0, stream>>>(agg, deg_in, W2,
                                                              b2, out, n_nodes);
}

// Round 10
// 192.446 us; speedup vs baseline: 1.0751x; 1.0751x over previous
//
#include <hip/hip_runtime.h>
#include <hip/hip_fp16.h>

#define D      64
#define BSHIFT 9
#define BSIZE  512    // nodes per bucket
#define NBMAX  256    // supports N <= 131072
#define CAP    8192   // edge capacity per bucket (lambda ~6.1k, 26 sigma)
#define CHUNK  4096   // binA LDS sort chunk

typedef _Float16 h2 __attribute__((ext_vector_type(2)));
union UH2 { unsigned u; h2 h; };

__device__ __forceinline__ unsigned short f2h(float f) {
    __half h = __float2half_rn(f);
    return *reinterpret_cast<unsigned short*>(&h);
}
__device__ __forceinline__ h2 u2h(unsigned u) { UH2 t; t.u = u; return t.h; }
__device__ __forceinline__ unsigned h2u(h2 h) { UH2 t; t.h = h; return t.u; }

// ===========================================================================
// binA: per-block LDS counting sort into NB coarse buckets (dst AND src keys),
// then COALESCED copy-out of dense per-bucket runs. Grid=512 x 512 threads
// (R4/R7 best. R3's grid=1024 halved copy-out run lengths -> regressed;
// 512 threads fixed the 18%-occupancy latency stall seen in R2.)
// ===========================================================================
__global__ void __launch_bounds__(512)
binA_kernel(const int* __restrict__ src, const int* __restrict__ dst,
            int* __restrict__ curD, int* __restrict__ curS,
            unsigned int* __restrict__ bufD,
            unsigned short* __restrict__ bufS, int n_edges) {
    __shared__ unsigned int   stD[CHUNK];
    __shared__ unsigned short stS[CHUNK];
    __shared__ unsigned char  stDB[CHUNK], stSB[CHUNK];
    __shared__ int histD[NBMAX], histS[NBMAX];
    __shared__ int offD[NBMAX], offS[NBMAX];
    __shared__ int bgD[NBMAX], bgS[NBMAX];
    __shared__ int wtD[4], wtS[4];

    int t = threadIdx.x;
    int per = (n_edges + gridDim.x - 1) / gridDim.x;
    int lo = blockIdx.x * per;
    int hi = min(lo + per, n_edges);

    for (int c0 = lo; c0 < hi; c0 += CHUNK) {
        int m = min(CHUNK, hi - c0);
        if (t < NBMAX) { histD[t] = 0; histS[t] = 0; }
        __syncthreads();
        for (int i = t; i < m; i += 512) {
            atomicAdd(&histD[dst[c0 + i] >> BSHIFT], 1);
            atomicAdd(&histS[src[c0 + i] >> BSHIFT], 1);
        }
        __syncthreads();
        int vD = 0, vS = 0, xD = 0, xS = 0;
        if (t < NBMAX) {                         // waves 0-3 only (uniform)
            vD = histD[t]; vS = histS[t];
            xD = vD; xS = vS;
            // wave-level inclusive scan (6 shfl steps, no barriers)
#pragma unroll
            for (int o = 1; o < 64; o <<= 1) {
                int yD = __shfl_up(xD, o, 64);
                int yS = __shfl_up(xS, o, 64);
                if ((t & 63) >= o) { xD += yD; xS += yS; }
            }
            if ((t & 63) == 63) { wtD[t >> 6] = xD; wtS[t >> 6] = xS; }
        }
        __syncthreads();
        if (t < NBMAX) {
            int baseD = 0, baseS = 0;
            for (int w = 0; w < (t >> 6); ++w) { baseD += wtD[w]; baseS += wtS[w]; }
            offD[t] = baseD + xD - vD;           // exclusive scan
            offS[t] = baseS + xS - vS;
            bgD[t] = vD ? atomicAdd(&curD[t], vD) : 0;
            bgS[t] = vS ? atomicAdd(&curS[t], vS) : 0;
        }
        __syncthreads();
        for (int i = t; i < m; i += 512) {       // LDS scatter (sorted)
            int s = src[c0 + i], d = dst[c0 + i];
            int bd = d >> BSHIFT;
            int p = atomicAdd(&offD[bd], 1);
            stD[p]  = (unsigned)s | ((unsigned)(d & (BSIZE - 1)) << 17);
            stDB[p] = (unsigned char)bd;
            int bs = s >> BSHIFT;
            int q = atomicAdd(&offS[bs], 1);
            stS[q]  = (unsigned short)(s & (BSIZE - 1));
            stSB[q] = (unsigned char)bs;
        }
        __syncthreads();
        for (int i = t; i < m; i += 512) {       // coalesced copy-out
            int bd = stDB[i];
            int lb = offD[bd] - histD[bd];       // excl base (off now = end)
            int gp = bgD[bd] + (i - lb);
            if (gp < CAP) bufD[(size_t)bd * CAP + gp] = stD[i];
            int bs = stSB[i];
            int lb2 = offS[bs] - histS[bs];
            int gq = bgS[bs] + (i - lb2);
            if (gq < CAP) bufS[(size_t)bs * CAP + gq] = stS[i];
        }
        __syncthreads();
    }
}

// ===========================================================================
// binBC: blocks [0,nb): counting-sort dst-bucket in LDS -> dense edge list
// (aliases bufD) + packed rpd = beg | (deg<<21).
// Blocks [nb, 5*nb): R7 split — each src bucket is handled by FOUR staging
// sub-blocks of 128 nodes (filtered histogram of the bucket's bufS), fixing
// the 392-blocks-on-256-CUs starvation of the feats->xp1 streaming pass.
// (R7: 188.1 µs, −6 vs R4.)
// ===========================================================================
__global__ void __launch_bounds__(512)
binBC_kernel(const unsigned int* __restrict__ bufD,
             unsigned int* __restrict__ edgeC,        // == bufD (alias)
             const unsigned short* __restrict__ bufS,
             const int* __restrict__ curD, const int* __restrict__ curS,
             unsigned int* __restrict__ rpd,
             float* __restrict__ norm_out,
             const float* __restrict__ feats,
             uint2* __restrict__ xp1,
             int n_nodes, int nb) {
    __shared__ int hist[BSIZE], off[BSIZE], cnt2[BSIZE];
    __shared__ int stage[CAP];
    __shared__ int wt[8];
    int b = blockIdx.x, t = threadIdx.x;

    if (b < nb) {
        hist[t] = 0;
        __syncthreads();
        int m = min(curD[b], CAP);
        for (int e = t; e < m; e += 512)
            atomicAdd(&hist[bufD[(size_t)b * CAP + e] >> 17], 1);
        __syncthreads();
        int v = hist[t];
        int x = v;
#pragma unroll
        for (int o = 1; o < 64; o <<= 1) {
            int y = __shfl_up(x, o, 64);
            if ((t & 63) >= o) x += y;
        }
        if ((t & 63) == 63) wt[t >> 6] = x;
        __syncthreads();
        int base = 0;
        for (int w = 0; w < (t >> 6); ++w) base += wt[w];
        int excl = base + x - v;
        off[t] = excl;
        cnt2[t] = 0;
        __syncthreads();
        for (int e = t; e < m; e += 512) {
            unsigned w = bufD[(size_t)b * CAP + e];
            int dl = w >> 17;
            int s  = (int)(w & 0x1FFFFu);
            int pos = off[dl] + atomicAdd(&cnt2[dl], 1);
            stage[pos] = s;
        }
        __syncthreads();
        for (int e = t; e < m; e += 512)
            edgeC[(size_t)b * CAP + e] = (unsigned)stage[e];
        int node = (b << BSHIFT) + t;
        if (node < n_nodes)
            rpd[node] = (unsigned)(b * CAP + excl) |
                        ((unsigned)min(v, 2047) << 21);
    } else {
        int bb  = b - nb;              // 0 .. 4*nb-1
        int b2  = bb >> 2;             // source bucket
        int sub = bb & 3;              // which 128-node sub-range
        int lo  = sub << 7;            // local-id range [lo, lo+128)
        int node0 = (b2 << BSHIFT) + lo;
        if (t < 128) hist[t] = 0;
        __syncthreads();
        int m = min(curS[b2], CAP);
        for (int e = t; e < m; e += 512) {
            int v = (int)bufS[(size_t)b2 * CAP + e];
            int l = v - lo;
            if ((unsigned)l < 128u) atomicAdd(&hist[l], 1);
        }
        __syncthreads();
        int node = node0 + t;
        if (t < 128 && node < n_nodes)
            norm_out[node] = rsqrtf(fmaxf((float)hist[t], 1.0f));
        // fused scale: xp1[row] = fp16(feats[row] * norm_out[row])
        int m2 = min(128, n_nodes - node0);
        for (int i = t; i < m2 * 16; i += 512) {
            int row = i >> 4, c = i & 15;
            float no = rsqrtf(fmaxf((float)hist[row], 1.0f));
            float4 vv = ((const float4*)feats)[(size_t)(node0 + row) * 16 + c];
            uint2 o;
            o.x = (unsigned)f2h(vv.x * no) | ((unsigned)f2h(vv.y * no) << 16);
            o.y = (unsigned)f2h(vv.z * no) | ((unsigned)f2h(vv.w * no) << 16);
            xp1[(size_t)(node0 + row) * 16 + c] = o;
        }
    }
}

// ===========================================================================
// Fused gather + GEMV, TWO rows per wave (lanes 0-31 row A, 32-63 row B).
// R10 = exact R7 body (best known: 188.1 µs) + s_setprio(1) around the
// reduce+GEMV cluster (T5): independent waves sit at different phases on a
// CU; a wave entering its serial VALU section gets issue priority over
// co-resident waves that are waiting on gather loads. Arithmetic untouched.
// (R8 manual pipelining: regressed. R9 W-in-LDS: occupancy up but ds_reads
// lengthened the serial chain — regressed. Keep W in VGPRs.)
// ===========================================================================
template <bool RELU, bool SCALE_OUT, bool OUT_HALF>
__global__ void __launch_bounds__(256)
gatherw_kernel(const unsigned int* __restrict__ xp,     // fp16 rows, 32 uints
               const unsigned int* __restrict__ rpd,
               const unsigned int* __restrict__ edgeC,
               const float* __restrict__ norm_out,
               const float* __restrict__ W,
               const float* __restrict__ bias,
               void* __restrict__ outv, int n_nodes) {
    __shared__ int eld[4][64];     // wave-private edge staging
    int lane   = threadIdx.x & 63;
    int wv     = threadIdx.x >> 6;
    int g      = lane >> 3, l8 = lane & 7;
    int half   = g >> 2;           // 0 -> row A, 1 -> row B
    int g4     = g & 3;            // group within my row (0..3)
    int base32 = lane & 32;
    int l32    = lane & 31;
    int wid  = (blockIdx.x * blockDim.x + threadIdx.x) >> 6;
    int nw   = (gridDim.x * blockDim.x) >> 6;

    // W pairs: wp[p] = (W[2p][lane], W[2p+1][lane]) as packed fp16
    h2 wp[32];
#pragma unroll
    for (int p = 0; p < 32; ++p) {
        h2 h;
        h.x = (_Float16)W[(2 * p) * D + lane];
        h.y = (_Float16)W[(2 * p + 1) * D + lane];
        wp[p] = h;
    }
    float bj = bias[lane];

    int npairs = (n_nodes + 1) >> 1;
    for (int pr = wid; pr < npairs; pr += nw) {
        int r0 = pr * 2;
        int rme = r0 + half;                    // row this half-wave gathers
        unsigned pk = (rme < n_nodes) ? rpd[rme] : 0u;
        int begme = (int)(pk & 0x1FFFFFu);
        int degme = (int)(pk >> 21);
        const unsigned int* el = edgeC + begme;

        int dmax = min(degme, 32);
        // one coalesced load per half; staged in LDS while fully converged
        eld[wv][lane] = (l32 < dmax) ? (int)el[l32] : 0;

        h2 a0 = (h2)0, a1 = (h2)0, a2 = (h2)0, a3 = (h2)0;
        int e = g4;
        for (; e + 4 < dmax; e += 8) {
            int s0 = eld[wv][base32 + e];
            int s1 = eld[wv][base32 + e + 4];
            uint4 u = *(const uint4*)(xp + (size_t)s0 * 32 + l8 * 4);
            uint4 v = *(const uint4*)(xp + (size_t)s1 * 32 + l8 * 4);
            a0 += u2h(u.x); a1 += u2h(u.y); a2 += u2h(u.z); a3 += u2h(u.w);
            a0 += u2h(v.x); a1 += u2h(v.y); a2 += u2h(v.z); a3 += u2h(v.w);
        }
        for (; e < dmax; e += 4) {
            int s0 = eld[wv][base32 + e];
            uint4 u = *(const uint4*)(xp + (size_t)s0 * 32 + l8 * 4);
            a0 += u2h(u.x); a1 += u2h(u.y); a2 += u2h(u.z); a3 += u2h(u.w);
        }
        for (int e2 = 32 + g4; e2 < degme; e2 += 4) {   // rare deg>32 tail
            int s0 = (int)el[e2];
            uint4 u = *(const uint4*)(xp + (size_t)s0 * 32 + l8 * 4);
            a0 += u2h(u.x); a1 += u2h(u.y); a2 += u2h(u.z); a3 += u2h(u.w);
        }

        // serial VALU cluster: boost issue priority over load-waiting waves
        __builtin_amdgcn_s_setprio(1);
        // reduce the 4 groups of each half (lane bits 3,4) — both rows at once
#pragma unroll
        for (int off = 8; off < 32; off <<= 1) {
            a0 += u2h(__shfl_xor(h2u(a0), off, 64));
            a1 += u2h(__shfl_xor(h2u(a1), off, 64));
            a2 += u2h(__shfl_xor(h2u(a2), off, 64));
            a3 += u2h(__shfl_xor(h2u(a3), off, 64));
        }
        // row A slice sums in lanes 0-7, row B in lanes 32-39
        unsigned au[4] = {h2u(a0), h2u(a1), h2u(a2), h2u(a3)};

        // dual GEMV: pair p of row A in lane p>>2, row B in lane 32+(p>>2)
        float accA = 0.0f, accB = 0.0f;
#pragma unroll
        for (int p = 0; p < 32; ++p) {
            UH2 ta, tb;
            ta.u = __builtin_amdgcn_readlane(au[p & 3], p >> 2);
            tb.u = __builtin_amdgcn_readlane(au[p & 3], 32 + (p >> 2));
            accA = __builtin_amdgcn_fdot2(ta.h, wp[p], accA, false);
            accB = __builtin_amdgcn_fdot2(tb.h, wp[p], accB, false);
        }
        __builtin_amdgcn_s_setprio(0);

        int degA = __builtin_amdgcn_readlane(degme, 0);
        int degB = __builtin_amdgcn_readlane(degme, 32);
        {
            float ni = rsqrtf(fmaxf((float)degA, 1.0f));
            float o  = fmaf(accA, ni, bj);
            if (RELU) o = fmaxf(o, 0.0f);
            if (SCALE_OUT) o *= norm_out[r0];
            if (OUT_HALF)
                ((unsigned short*)outv)[(size_t)r0 * D + lane] = f2h(o);
            else
                ((float*)outv)[(size_t)r0 * D + lane] = o;
        }
        if (r0 + 1 < n_nodes) {
            float ni = rsqrtf(fmaxf((float)degB, 1.0f));
            float o  = fmaf(accB, ni, bj);
            if (RELU) o = fmaxf(o, 0.0f);
            if (SCALE_OUT) o *= norm_out[r0 + 1];
            if (OUT_HALF)
                ((unsigned short*)outv)[(size_t)(r0 + 1) * D + lane] = f2h(o);
            else
                ((float*)outv)[(size_t)(r0 + 1) * D + lane] = o;
        }
    }
}

// ===========================================================================
// Minimal fallback (R1 atomic path) — only if workspace is tiny
// ===========================================================================
__global__ void degree_kernel(const int* __restrict__ src,
                              const int* __restrict__ dst,
                              float* __restrict__ deg_out,
                              float* __restrict__ deg_in, int n_edges) {
    int e = blockIdx.x * blockDim.x + threadIdx.x;
    if (e < n_edges) {
        atomicAdd(&deg_out[src[e]], 1.0f);
        atomicAdd(&deg_in[dst[e]], 1.0f);
    }
}
__global__ void norm_kernel(float* __restrict__ deg, int n) {
    int i = blockIdx.x * blockDim.x + threadIdx.x;
    if (i < n) deg[i] = rsqrtf(fmaxf(deg[i], 1.0f));
}
__global__ void spmm_kernel(const float* __restrict__ x,
                            const int* __restrict__ src,
                            const int* __restrict__ dst,
                            const float* __restrict__ norm_out,
                            float* __restrict__ agg, int n_edges) {
    int gid = blockIdx.x * blockDim.x + threadIdx.x;
    int e = gid >> 6, lane = threadIdx.x & 63;
    if (e < n_edges) {
        int s = src[e], d = dst[e];
        atomicAdd(&agg[(size_t)d * D + lane],
                  x[(size_t)s * D + lane] * norm_out[s]);
    }
}
template <bool RELU>
__global__ void gemm_kernel(const float* __restrict__ agg,
                            const float* __restrict__ norm_in,
                            const float* __restrict__ W,
                            const float* __restrict__ b,
                            float* __restrict__ out, int n_nodes) {
    __shared__ float Wl[D * D];
    for (int i = threadIdx.x; i < D * D; i += blockDim.x) Wl[i] = W[i];
    __syncthreads();
    int lane = threadIdx.x & 63, wave = threadIdx.x >> 6;
    int wpb = blockDim.x >> 6;
    float bj = b[lane];
    for (int row = blockIdx.x * wpb + wave; row < n_nodes;
         row += gridDim.x * wpb) {
        float aa = agg[(size_t)row * D + lane] * norm_in[row];
        float acc = bj;
#pragma unroll
        for (int k = 0; k < D; ++k)
            acc = fmaf(__shfl(aa, k, 64), Wl[k * D + lane], acc);
        if (RELU) acc = fmaxf(acc, 0.0f);
        out[(size_t)row * D + lane] = acc;
    }
}

// ===========================================================================
// Launch
// ===========================================================================
extern "C" void kernel_launch(void* const* d_in, const int* in_sizes, int n_in,
                              void* d_out, int out_size, void* d_ws, size_t ws_size,
                              hipStream_t stream) {
    const float* feats = (const float*)d_in[0];
    const int*   src   = (const int*)  d_in[1];
    const int*   dst   = (const int*)  d_in[2];
    const float* W1    = (const float*)d_in[3];
    const float* b1    = (const float*)d_in[4];
    const float* W2    = (const float*)d_in[5];
    const float* b2    = (const float*)d_in[6];
    float*       out   = (float*)d_out;

    const int n_nodes = in_sizes[0] / D;   // 100000
    const int n_edges = in_sizes[1];       // 1200000
    const size_t nd = (size_t)n_nodes * D;
    const int nb = (n_nodes + BSIZE - 1) >> BSHIFT;

    // Layout: [bufD nb*CAP u32 (reused as edgeC)][bufS nb*CAP u16]
    //         [xp1 half N*D][xa half N*D][rpd N][norm_out N][curD 256][curS 256]
    size_t bufD_sz = (size_t)nb * CAP * 4;
    size_t bufS_sz = (size_t)nb * CAP * 2;
    size_t need = bufD_sz + bufS_sz + nd * 2 * 2 + (size_t)n_nodes * 8 + 2048;

    if (ws_size >= need && nb <= NBMAX && (size_t)nb * CAP < (1u << 21)) {
        char* base = (char*)d_ws;
        unsigned int*   bufD = (unsigned int*)base;
        unsigned short* bufS = (unsigned short*)(base + bufD_sz);
        unsigned int*   xp1  = (unsigned int*)(base + bufD_sz + bufS_sz);
        unsigned int*   xa   = (unsigned int*)((char*)xp1 + nd * 2);
        unsigned int*   rpd  = (unsigned int*)((char*)xa + nd * 2);
        float* norm_out = (float*)(rpd + n_nodes);
        int*   curD     = (int*)(norm_out + n_nodes);
        int*   curS     = curD + 256;

        hipMemsetAsync(curD, 0, 2048, stream);
        binA_kernel<<<512, 512, 0, stream>>>(src, dst, curD, curS, bufD, bufS,
                                             n_edges);
        binBC_kernel<<<5 * nb, 512, 0, stream>>>(bufD, bufD, bufS, curD, curS,
                                                 rpd, norm_out,
                                                 feats, (uint2*)xp1,
                                                 n_nodes, nb);

        // Layer 1: xp1 -> xa (fp16, pre-scaled by norm_out for next layer)
        gatherw_kernel<true, true, true><<<6400, 256, 0, stream>>>(
            xp1, rpd, bufD, norm_out, W1, b1, xa, n_nodes);
        // Layer 2: xa -> final fp32 out
        gatherw_kernel<false, false, false><<<6400, 256, 0, stream>>>(
            xa, rpd, bufD, norm_out, W2, b2, out, n_nodes);
        return;
    }

    // ---------------- fallback: R1 atomic path ----------------
    float* deg_out = (float*)d_ws;
    float* deg_in  = deg_out + n_nodes;
    float* agg     = deg_in + n_nodes;
    float* x       = out;

    hipMemsetAsync(d_ws, 0, (2 * (size_t)n_nodes + nd) * sizeof(float), stream);
    degree_kernel<<<(n_edges + 255) / 256, 256, 0, stream>>>(src, dst, deg_out,
                                                             deg_in, n_edges);
    norm_kernel<<<(2 * n_nodes + 255) / 256, 256, 0, stream>>>(deg_out,
                                                               2 * n_nodes);
    {
        long long threads = (long long)n_edges * 64;
        int blocks = (int)((threads + 255) / 256);
        spmm_kernel<<<blocks, 256, 0, stream>>>(feats, src, dst, deg_out, agg,
                                                n_edges);
    }
    gemm_kernel<true><<<(n_nodes + 3) / 4, 256, 0, stream>>>(agg, deg_in, W1,
                                                             b1, x, n_nodes);
    hipMemsetAsync(agg, 0, nd * sizeof(float), stream);
    {
        long long threads = (long long)n_edges * 64;
        int blocks = (int)((threads + 255) / 256);
        spmm_kernel<<<blocks, 256, 0, stream>>>(x, src, dst, deg_out, agg,
                                                n_edges);
    }
    gemm_kernel<false><<<(n_nodes + 3) / 4, 256, 0, stream>>>(agg, deg_in, W2,
                                                              b2, out, n_nodes);
}

// Round 11
// 189.339 us; speedup vs baseline: 1.0927x; 1.0164x over previous
//
#include <hip/hip_runtime.h>
#include <hip/hip_fp16.h>

#define D      64
#define BSHIFT 9
#define BSIZE  512    // nodes per bucket
#define NBMAX  256    // supports N <= 131072
#define CAP    8192   // edge capacity per bucket (lambda ~6.1k, 26 sigma)
#define CHUNK  4096   // binA LDS sort chunk

typedef _Float16 h2 __attribute__((ext_vector_type(2)));
union UH2 { unsigned u; h2 h; };

__device__ __forceinline__ unsigned short f2h(float f) {
    __half h = __float2half_rn(f);
    return *reinterpret_cast<unsigned short*>(&h);
}
__device__ __forceinline__ h2 u2h(unsigned u) { UH2 t; t.u = u; return t.h; }
__device__ __forceinline__ unsigned h2u(h2 h) { UH2 t; t.h = h; return t.u; }

// ===========================================================================
// binA: per-block LDS counting sort into NB coarse buckets (dst AND src keys),
// then COALESCED copy-out of dense per-bucket runs. Grid=512 x 512 threads
// (R4/R7 best. R3's grid=1024 halved copy-out run lengths -> regressed;
// 512 threads fixed the 18%-occupancy latency stall seen in R2.)
// ===========================================================================
__global__ void __launch_bounds__(512)
binA_kernel(const int* __restrict__ src, const int* __restrict__ dst,
            int* __restrict__ curD, int* __restrict__ curS,
            unsigned int* __restrict__ bufD,
            unsigned short* __restrict__ bufS, int n_edges) {
    __shared__ unsigned int   stD[CHUNK];
    __shared__ unsigned short stS[CHUNK];
    __shared__ unsigned char  stDB[CHUNK], stSB[CHUNK];
    __shared__ int histD[NBMAX], histS[NBMAX];
    __shared__ int offD[NBMAX], offS[NBMAX];
    __shared__ int bgD[NBMAX], bgS[NBMAX];
    __shared__ int wtD[4], wtS[4];

    int t = threadIdx.x;
    int per = (n_edges + gridDim.x - 1) / gridDim.x;
    int lo = blockIdx.x * per;
    int hi = min(lo + per, n_edges);

    for (int c0 = lo; c0 < hi; c0 += CHUNK) {
        int m = min(CHUNK, hi - c0);
        if (t < NBMAX) { histD[t] = 0; histS[t] = 0; }
        __syncthreads();
        for (int i = t; i < m; i += 512) {
            atomicAdd(&histD[dst[c0 + i] >> BSHIFT], 1);
            atomicAdd(&histS[src[c0 + i] >> BSHIFT], 1);
        }
        __syncthreads();
        int vD = 0, vS = 0, xD = 0, xS = 0;
        if (t < NBMAX) {                         // waves 0-3 only (uniform)
            vD = histD[t]; vS = histS[t];
            xD = vD; xS = vS;
            // wave-level inclusive scan (6 shfl steps, no barriers)
#pragma unroll
            for (int o = 1; o < 64; o <<= 1) {
                int yD = __shfl_up(xD, o, 64);
                int yS = __shfl_up(xS, o, 64);
                if ((t & 63) >= o) { xD += yD; xS += yS; }
            }
            if ((t & 63) == 63) { wtD[t >> 6] = xD; wtS[t >> 6] = xS; }
        }
        __syncthreads();
        if (t < NBMAX) {
            int baseD = 0, baseS = 0;
            for (int w = 0; w < (t >> 6); ++w) { baseD += wtD[w]; baseS += wtS[w]; }
            offD[t] = baseD + xD - vD;           // exclusive scan
            offS[t] = baseS + xS - vS;
            bgD[t] = vD ? atomicAdd(&curD[t], vD) : 0;
            bgS[t] = vS ? atomicAdd(&curS[t], vS) : 0;
        }
        __syncthreads();
        for (int i = t; i < m; i += 512) {       // LDS scatter (sorted)
            int s = src[c0 + i], d = dst[c0 + i];
            int bd = d >> BSHIFT;
            int p = atomicAdd(&offD[bd], 1);
            stD[p]  = (unsigned)s | ((unsigned)(d & (BSIZE - 1)) << 17);
            stDB[p] = (unsigned char)bd;
            int bs = s >> BSHIFT;
            int q = atomicAdd(&offS[bs], 1);
            stS[q]  = (unsigned short)(s & (BSIZE - 1));
            stSB[q] = (unsigned char)bs;
        }
        __syncthreads();
        for (int i = t; i < m; i += 512) {       // coalesced copy-out
            int bd = stDB[i];
            int lb = offD[bd] - histD[bd];       // excl base (off now = end)
            int gp = bgD[bd] + (i - lb);
            if (gp < CAP) bufD[(size_t)bd * CAP + gp] = stD[i];
            int bs = stSB[i];
            int lb2 = offS[bs] - histS[bs];
            int gq = bgS[bs] + (i - lb2);
            if (gq < CAP) bufS[(size_t)bs * CAP + gq] = stS[i];
        }
        __syncthreads();
    }
}

// ===========================================================================
// binBC: blocks [0,nb): counting-sort dst-bucket in LDS -> dense edge list
// (aliases bufD) + packed rpd = beg | (deg<<21).
// Blocks [nb, 5*nb): R7 split — each src bucket is handled by FOUR staging
// sub-blocks of 128 nodes (filtered histogram of the bucket's bufS), fixing
// the 392-blocks-on-256-CUs starvation of the feats->xp1 streaming pass.
// (R7: 188.1 µs, −6 vs R4.)
// ===========================================================================
__global__ void __launch_bounds__(512)
binBC_kernel(const unsigned int* __restrict__ bufD,
             unsigned int* __restrict__ edgeC,        // == bufD (alias)
             const unsigned short* __restrict__ bufS,
             const int* __restrict__ curD, const int* __restrict__ curS,
             unsigned int* __restrict__ rpd,
             float* __restrict__ norm_out,
             const float* __restrict__ feats,
             uint2* __restrict__ xp1,
             int n_nodes, int nb) {
    __shared__ int hist[BSIZE], off[BSIZE], cnt2[BSIZE];
    __shared__ int stage[CAP];
    __shared__ int wt[8];
    int b = blockIdx.x, t = threadIdx.x;

    if (b < nb) {
        hist[t] = 0;
        __syncthreads();
        int m = min(curD[b], CAP);
        for (int e = t; e < m; e += 512)
            atomicAdd(&hist[bufD[(size_t)b * CAP + e] >> 17], 1);
        __syncthreads();
        int v = hist[t];
        int x = v;
#pragma unroll
        for (int o = 1; o < 64; o <<= 1) {
            int y = __shfl_up(x, o, 64);
            if ((t & 63) >= o) x += y;
        }
        if ((t & 63) == 63) wt[t >> 6] = x;
        __syncthreads();
        int base = 0;
        for (int w = 0; w < (t >> 6); ++w) base += wt[w];
        int excl = base + x - v;
        off[t] = excl;
        cnt2[t] = 0;
        __syncthreads();
        for (int e = t; e < m; e += 512) {
            unsigned w = bufD[(size_t)b * CAP + e];
            int dl = w >> 17;
            int s  = (int)(w & 0x1FFFFu);
            int pos = off[dl] + atomicAdd(&cnt2[dl], 1);
            stage[pos] = s;
        }
        __syncthreads();
        for (int e = t; e < m; e += 512)
            edgeC[(size_t)b * CAP + e] = (unsigned)stage[e];
        int node = (b << BSHIFT) + t;
        if (node < n_nodes)
            rpd[node] = (unsigned)(b * CAP + excl) |
                        ((unsigned)min(v, 2047) << 21);
    } else {
        int bb  = b - nb;              // 0 .. 4*nb-1
        int b2  = bb >> 2;             // source bucket
        int sub = bb & 3;              // which 128-node sub-range
        int lo  = sub << 7;            // local-id range [lo, lo+128)
        int node0 = (b2 << BSHIFT) + lo;
        if (t < 128) hist[t] = 0;
        __syncthreads();
        int m = min(curS[b2], CAP);
        for (int e = t; e < m; e += 512) {
            int v = (int)bufS[(size_t)b2 * CAP + e];
            int l = v - lo;
            if ((unsigned)l < 128u) atomicAdd(&hist[l], 1);
        }
        __syncthreads();
        int node = node0 + t;
        if (t < 128 && node < n_nodes)
            norm_out[node] = rsqrtf(fmaxf((float)hist[t], 1.0f));
        // fused scale: xp1[row] = fp16(feats[row] * norm_out[row])
        int m2 = min(128, n_nodes - node0);
        for (int i = t; i < m2 * 16; i += 512) {
            int row = i >> 4, c = i & 15;
            float no = rsqrtf(fmaxf((float)hist[row], 1.0f));
            float4 vv = ((const float4*)feats)[(size_t)(node0 + row) * 16 + c];
            uint2 o;
            o.x = (unsigned)f2h(vv.x * no) | ((unsigned)f2h(vv.y * no) << 16);
            o.y = (unsigned)f2h(vv.z * no) | ((unsigned)f2h(vv.w * no) << 16);
            xp1[(size_t)(node0 + row) * 16 + c] = o;
        }
    }
}

// ===========================================================================
// Fused gather + GEMV, TWO rows per wave (lanes 0-31 row A, 32-63 row B).
// Exact R7 body — best verified (188.1 µs). Subsequent experiments all
// bounced off the per-pair serial chain: R5/R6 split (48 µs latency-pinned
// standalone GEMV), R8 manual pipelining (compiler already hoists), R9
// W-in-LDS occupancy 2x (ds_reads lengthened the chain), R10 setprio
// (neutral). Keeping W in VGPRs, plain loop, no setprio.
// ===========================================================================
template <bool RELU, bool SCALE_OUT, bool OUT_HALF>
__global__ void __launch_bounds__(256)
gatherw_kernel(const unsigned int* __restrict__ xp,     // fp16 rows, 32 uints
               const unsigned int* __restrict__ rpd,
               const unsigned int* __restrict__ edgeC,
               const float* __restrict__ norm_out,
               const float* __restrict__ W,
               const float* __restrict__ bias,
               void* __restrict__ outv, int n_nodes) {
    __shared__ int eld[4][64];     // wave-private edge staging
    int lane   = threadIdx.x & 63;
    int wv     = threadIdx.x >> 6;
    int g      = lane >> 3, l8 = lane & 7;
    int half   = g >> 2;           // 0 -> row A, 1 -> row B
    int g4     = g & 3;            // group within my row (0..3)
    int base32 = lane & 32;
    int l32    = lane & 31;
    int wid  = (blockIdx.x * blockDim.x + threadIdx.x) >> 6;
    int nw   = (gridDim.x * blockDim.x) >> 6;

    // W pairs: wp[p] = (W[2p][lane], W[2p+1][lane]) as packed fp16
    h2 wp[32];
#pragma unroll
    for (int p = 0; p < 32; ++p) {
        h2 h;
        h.x = (_Float16)W[(2 * p) * D + lane];
        h.y = (_Float16)W[(2 * p + 1) * D + lane];
        wp[p] = h;
    }
    float bj = bias[lane];

    int npairs = (n_nodes + 1) >> 1;
    for (int pr = wid; pr < npairs; pr += nw) {
        int r0 = pr * 2;
        int rme = r0 + half;                    // row this half-wave gathers
        unsigned pk = (rme < n_nodes) ? rpd[rme] : 0u;
        int begme = (int)(pk & 0x1FFFFFu);
        int degme = (int)(pk >> 21);
        const unsigned int* el = edgeC + begme;

        int dmax = min(degme, 32);
        // one coalesced load per half; staged in LDS while fully converged
        eld[wv][lane] = (l32 < dmax) ? (int)el[l32] : 0;

        h2 a0 = (h2)0, a1 = (h2)0, a2 = (h2)0, a3 = (h2)0;
        int e = g4;
        for (; e + 4 < dmax; e += 8) {
            int s0 = eld[wv][base32 + e];
            int s1 = eld[wv][base32 + e + 4];
            uint4 u = *(const uint4*)(xp + (size_t)s0 * 32 + l8 * 4);
            uint4 v = *(const uint4*)(xp + (size_t)s1 * 32 + l8 * 4);
            a0 += u2h(u.x); a1 += u2h(u.y); a2 += u2h(u.z); a3 += u2h(u.w);
            a0 += u2h(v.x); a1 += u2h(v.y); a2 += u2h(v.z); a3 += u2h(v.w);
        }
        for (; e < dmax; e += 4) {
            int s0 = eld[wv][base32 + e];
            uint4 u = *(const uint4*)(xp + (size_t)s0 * 32 + l8 * 4);
            a0 += u2h(u.x); a1 += u2h(u.y); a2 += u2h(u.z); a3 += u2h(u.w);
        }
        for (int e2 = 32 + g4; e2 < degme; e2 += 4) {   // rare deg>32 tail
            int s0 = (int)el[e2];
            uint4 u = *(const uint4*)(xp + (size_t)s0 * 32 + l8 * 4);
            a0 += u2h(u.x); a1 += u2h(u.y); a2 += u2h(u.z); a3 += u2h(u.w);
        }
        // reduce the 4 groups of each half (lane bits 3,4) — both rows at once
#pragma unroll
        for (int off = 8; off < 32; off <<= 1) {
            a0 += u2h(__shfl_xor(h2u(a0), off, 64));
            a1 += u2h(__shfl_xor(h2u(a1), off, 64));
            a2 += u2h(__shfl_xor(h2u(a2), off, 64));
            a3 += u2h(__shfl_xor(h2u(a3), off, 64));
        }
        // row A slice sums in lanes 0-7, row B in lanes 32-39
        unsigned au[4] = {h2u(a0), h2u(a1), h2u(a2), h2u(a3)};

        // dual GEMV: pair p of row A in lane p>>2, row B in lane 32+(p>>2)
        float accA = 0.0f, accB = 0.0f;
#pragma unroll
        for (int p = 0; p < 32; ++p) {
            UH2 ta, tb;
            ta.u = __builtin_amdgcn_readlane(au[p & 3], p >> 2);
            tb.u = __builtin_amdgcn_readlane(au[p & 3], 32 + (p >> 2));
            accA = __builtin_amdgcn_fdot2(ta.h, wp[p], accA, false);
            accB = __builtin_amdgcn_fdot2(tb.h, wp[p], accB, false);
        }

        int degA = __builtin_amdgcn_readlane(degme, 0);
        int degB = __builtin_amdgcn_readlane(degme, 32);
        {
            float ni = rsqrtf(fmaxf((float)degA, 1.0f));
            float o  = fmaf(accA, ni, bj);
            if (RELU) o = fmaxf(o, 0.0f);
            if (SCALE_OUT) o *= norm_out[r0];
            if (OUT_HALF)
                ((unsigned short*)outv)[(size_t)r0 * D + lane] = f2h(o);
            else
                ((float*)outv)[(size_t)r0 * D + lane] = o;
        }
        if (r0 + 1 < n_nodes) {
            float ni = rsqrtf(fmaxf((float)degB, 1.0f));
            float o  = fmaf(accB, ni, bj);
            if (RELU) o = fmaxf(o, 0.0f);
            if (SCALE_OUT) o *= norm_out[r0 + 1];
            if (OUT_HALF)
                ((unsigned short*)outv)[(size_t)(r0 + 1) * D + lane] = f2h(o);
            else
                ((float*)outv)[(size_t)(r0 + 1) * D + lane] = o;
        }
    }
}

// ===========================================================================
// Minimal fallback (R1 atomic path) — only if workspace is tiny
// ===========================================================================
__global__ void degree_kernel(const int* __restrict__ src,
                              const int* __restrict__ dst,
                              float* __restrict__ deg_out,
                              float* __restrict__ deg_in, int n_edges) {
    int e = blockIdx.x * blockDim.x + threadIdx.x;
    if (e < n_edges) {
        atomicAdd(&deg_out[src[e]], 1.0f);
        atomicAdd(&deg_in[dst[e]], 1.0f);
    }
}
__global__ void norm_kernel(float* __restrict__ deg, int n) {
    int i = blockIdx.x * blockDim.x + threadIdx.x;
    if (i < n) deg[i] = rsqrtf(fmaxf(deg[i], 1.0f));
}
__global__ void spmm_kernel(const float* __restrict__ x,
                            const int* __restrict__ src,
                            const int* __restrict__ dst,
                            const float* __restrict__ norm_out,
                            float* __restrict__ agg, int n_edges) {
    int gid = blockIdx.x * blockDim.x + threadIdx.x;
    int e = gid >> 6, lane = threadIdx.x & 63;
    if (e < n_edges) {
        int s = src[e], d = dst[e];
        atomicAdd(&agg[(size_t)d * D + lane],
                  x[(size_t)s * D + lane] * norm_out[s]);
    }
}
template <bool RELU>
__global__ void gemm_kernel(const float* __restrict__ agg,
                            const float* __restrict__ norm_in,
                            const float* __restrict__ W,
                            const float* __restrict__ b,
                            float* __restrict__ out, int n_nodes) {
    __shared__ float Wl[D * D];
    for (int i = threadIdx.x; i < D * D; i += blockDim.x) Wl[i] = W[i];
    __syncthreads();
    int lane = threadIdx.x & 63, wave = threadIdx.x >> 6;
    int wpb = blockDim.x >> 6;
    float bj = b[lane];
    for (int row = blockIdx.x * wpb + wave; row < n_nodes;
         row += gridDim.x * wpb) {
        float aa = agg[(size_t)row * D + lane] * norm_in[row];
        float acc = bj;
#pragma unroll
        for (int k = 0; k < D; ++k)
            acc = fmaf(__shfl(aa, k, 64), Wl[k * D + lane], acc);
        if (RELU) acc = fmaxf(acc, 0.0f);
        out[(size_t)row * D + lane] = acc;
    }
}

// ===========================================================================
// Launch
// ===========================================================================
extern "C" void kernel_launch(void* const* d_in, const int* in_sizes, int n_in,
                              void* d_out, int out_size, void* d_ws, size_t ws_size,
                              hipStream_t stream) {
    const float* feats = (const float*)d_in[0];
    const int*   src   = (const int*)  d_in[1];
    const int*   dst   = (const int*)  d_in[2];
    const float* W1    = (const float*)d_in[3];
    const float* b1    = (const float*)d_in[4];
    const float* W2    = (const float*)d_in[5];
    const float* b2    = (const float*)d_in[6];
    float*       out   = (float*)d_out;

    const int n_nodes = in_sizes[0] / D;   // 100000
    const int n_edges = in_sizes[1];       // 1200000
    const size_t nd = (size_t)n_nodes * D;
    const int nb = (n_nodes + BSIZE - 1) >> BSHIFT;

    // Layout: [bufD nb*CAP u32 (reused as edgeC)][bufS nb*CAP u16]
    //         [xp1 half N*D][xa half N*D][rpd N][norm_out N][curD 256][curS 256]
    size_t bufD_sz = (size_t)nb * CAP * 4;
    size_t bufS_sz = (size_t)nb * CAP * 2;
    size_t need = bufD_sz + bufS_sz + nd * 2 * 2 + (size_t)n_nodes * 8 + 2048;

    if (ws_size >= need && nb <= NBMAX && (size_t)nb * CAP < (1u << 21)) {
        char* base = (char*)d_ws;
        unsigned int*   bufD = (unsigned int*)base;
        unsigned short* bufS = (unsigned short*)(base + bufD_sz);
        unsigned int*   xp1  = (unsigned int*)(base + bufD_sz + bufS_sz);
        unsigned int*   xa   = (unsigned int*)((char*)xp1 + nd * 2);
        unsigned int*   rpd  = (unsigned int*)((char*)xa + nd * 2);
        float* norm_out = (float*)(rpd + n_nodes);
        int*   curD     = (int*)(norm_out + n_nodes);
        int*   curS     = curD + 256;

        hipMemsetAsync(curD, 0, 2048, stream);
        binA_kernel<<<512, 512, 0, stream>>>(src, dst, curD, curS, bufD, bufS,
                                             n_edges);
        binBC_kernel<<<5 * nb, 512, 0, stream>>>(bufD, bufD, bufS, curD, curS,
                                                 rpd, norm_out,
                                                 feats, (uint2*)xp1,
                                                 n_nodes, nb);

        // Layer 1: xp1 -> xa (fp16, pre-scaled by norm_out for next layer)
        gatherw_kernel<true, true, true><<<6400, 256, 0, stream>>>(
            xp1, rpd, bufD, norm_out, W1, b1, xa, n_nodes);
        // Layer 2: xa -> final fp32 out
        gatherw_kernel<false, false, false><<<6400, 256, 0, stream>>>(
            xa, rpd, bufD, norm_out, W2, b2, out, n_nodes);
        return;
    }

    // ---------------- fallback: R1 atomic path ----------------
    float* deg_out = (float*)d_ws;
    float* deg_in  = deg_out + n_nodes;
    float* agg     = deg_in + n_nodes;
    float* x       = out;

    hipMemsetAsync(d_ws, 0, (2 * (size_t)n_nodes + nd) * sizeof(float), stream);
    degree_kernel<<<(n_edges + 255) / 256, 256, 0, stream>>>(src, dst, deg_out,
                                                             deg_in, n_edges);
    norm_kernel<<<(2 * n_nodes + 255) / 256, 256, 0, stream>>>(deg_out,
                                                               2 * n_nodes);
    {
        long long threads = (long long)n_edges * 64;
        int blocks = (int)((threads + 255) / 256);
        spmm_kernel<<<blocks, 256, 0, stream>>>(feats, src, dst, deg_out, agg,
                                                n_edges);
    }
    gemm_kernel<true><<<(n_nodes + 3) / 4, 256, 0, stream>>>(agg, deg_in, W1,
                                                             b1, x, n_nodes);
    hipMemsetAsync(agg, 0, nd * sizeof(float), stream);
    {
        long long threads = (long long)n_edges * 64;
        int blocks = (int)((threads + 255) / 256);
        spmm_kernel<<<blocks, 256, 0, stream>>>(x, src, dst, deg_out, agg,
                                                n_edges);
    }
    gemm_kernel<false><<<(n_nodes + 3) / 4, 256, 0, stream>>>(agg, deg_in, W2,
                                                              b2, out, n_nodes);
}

// Round 12
// 186.920 us; speedup vs baseline: 1.1069x; 1.0129x over previous
//
#include <hip/hip_runtime.h>
#include <hip/hip_fp16.h>

#define D      64
#define BSHIFT 9
#define BSIZE  512    // nodes per bucket
#define NBMAX  256    // supports N <= 131072
#define CAP    8192   // edge capacity per bucket (lambda ~6.1k, 26 sigma)
#define CHUNK  4096   // binA LDS sort chunk

typedef _Float16 h2 __attribute__((ext_vector_type(2)));
union UH2 { unsigned u; h2 h; };

__device__ __forceinline__ unsigned short f2h(float f) {
    __half h = __float2half_rn(f);
    return *reinterpret_cast<unsigned short*>(&h);
}
__device__ __forceinline__ h2 u2h(unsigned u) { UH2 t; t.u = u; return t.h; }
__device__ __forceinline__ unsigned h2u(h2 h) { UH2 t; t.h = h; return t.u; }

// ===========================================================================
// binA: per-block LDS counting sort into NB coarse buckets (dst AND src keys),
// then COALESCED copy-out of dense per-bucket runs. Grid=512 x 512 threads
// (R4/R7 best. R3's grid=1024 halved copy-out run lengths -> regressed;
// 512 threads fixed the 18%-occupancy latency stall seen in R2.)
// ===========================================================================
__global__ void __launch_bounds__(512)
binA_kernel(const int* __restrict__ src, const int* __restrict__ dst,
            int* __restrict__ curD, int* __restrict__ curS,
            unsigned int* __restrict__ bufD,
            unsigned short* __restrict__ bufS, int n_edges) {
    __shared__ unsigned int   stD[CHUNK];
    __shared__ unsigned short stS[CHUNK];
    __shared__ unsigned char  stDB[CHUNK], stSB[CHUNK];
    __shared__ int histD[NBMAX], histS[NBMAX];
    __shared__ int offD[NBMAX], offS[NBMAX];
    __shared__ int bgD[NBMAX], bgS[NBMAX];
    __shared__ int wtD[4], wtS[4];

    int t = threadIdx.x;
    int per = (n_edges + gridDim.x - 1) / gridDim.x;
    int lo = blockIdx.x * per;
    int hi = min(lo + per, n_edges);

    for (int c0 = lo; c0 < hi; c0 += CHUNK) {
        int m = min(CHUNK, hi - c0);
        if (t < NBMAX) { histD[t] = 0; histS[t] = 0; }
        __syncthreads();
        for (int i = t; i < m; i += 512) {
            atomicAdd(&histD[dst[c0 + i] >> BSHIFT], 1);
            atomicAdd(&histS[src[c0 + i] >> BSHIFT], 1);
        }
        __syncthreads();
        int vD = 0, vS = 0, xD = 0, xS = 0;
        if (t < NBMAX) {                         // waves 0-3 only (uniform)
            vD = histD[t]; vS = histS[t];
            xD = vD; xS = vS;
            // wave-level inclusive scan (6 shfl steps, no barriers)
#pragma unroll
            for (int o = 1; o < 64; o <<= 1) {
                int yD = __shfl_up(xD, o, 64);
                int yS = __shfl_up(xS, o, 64);
                if ((t & 63) >= o) { xD += yD; xS += yS; }
            }
            if ((t & 63) == 63) { wtD[t >> 6] = xD; wtS[t >> 6] = xS; }
        }
        __syncthreads();
        if (t < NBMAX) {
            int baseD = 0, baseS = 0;
            for (int w = 0; w < (t >> 6); ++w) { baseD += wtD[w]; baseS += wtS[w]; }
            offD[t] = baseD + xD - vD;           // exclusive scan
            offS[t] = baseS + xS - vS;
            bgD[t] = vD ? atomicAdd(&curD[t], vD) : 0;
            bgS[t] = vS ? atomicAdd(&curS[t], vS) : 0;
        }
        __syncthreads();
        for (int i = t; i < m; i += 512) {       // LDS scatter (sorted)
            int s = src[c0 + i], d = dst[c0 + i];
            int bd = d >> BSHIFT;
            int p = atomicAdd(&offD[bd], 1);
            stD[p]  = (unsigned)s | ((unsigned)(d & (BSIZE - 1)) << 17);
            stDB[p] = (unsigned char)bd;
            int bs = s >> BSHIFT;
            int q = atomicAdd(&offS[bs], 1);
            stS[q]  = (unsigned short)(s & (BSIZE - 1));
            stSB[q] = (unsigned char)bs;
        }
        __syncthreads();
        for (int i = t; i < m; i += 512) {       // coalesced copy-out
            int bd = stDB[i];
            int lb = offD[bd] - histD[bd];       // excl base (off now = end)
            int gp = bgD[bd] + (i - lb);
            if (gp < CAP) bufD[(size_t)bd * CAP + gp] = stD[i];
            int bs = stSB[i];
            int lb2 = offS[bs] - histS[bs];
            int gq = bgS[bs] + (i - lb2);
            if (gq < CAP) bufS[(size_t)bs * CAP + gq] = stS[i];
        }
        __syncthreads();
    }
}

// ===========================================================================
// binBC: blocks [0,nb): counting-sort dst-bucket in LDS -> dense edge list
// (aliases bufD) + packed rpd = beg | (deg<<21).
// Blocks [nb, 5*nb): R7 split — each src bucket is handled by FOUR staging
// sub-blocks of 128 nodes (filtered histogram of the bucket's bufS), fixing
// the 392-blocks-on-256-CUs starvation of the feats->xp1 streaming pass.
// (R7: 188.1 µs; R11 replay 189.3 — stable.)
// ===========================================================================
__global__ void __launch_bounds__(512)
binBC_kernel(const unsigned int* __restrict__ bufD,
             unsigned int* __restrict__ edgeC,        // == bufD (alias)
             const unsigned short* __restrict__ bufS,
             const int* __restrict__ curD, const int* __restrict__ curS,
             unsigned int* __restrict__ rpd,
             float* __restrict__ norm_out,
             const float* __restrict__ feats,
             uint2* __restrict__ xp1,
             int n_nodes, int nb) {
    __shared__ int hist[BSIZE], off[BSIZE], cnt2[BSIZE];
    __shared__ int stage[CAP];
    __shared__ int wt[8];
    int b = blockIdx.x, t = threadIdx.x;

    if (b < nb) {
        hist[t] = 0;
        __syncthreads();
        int m = min(curD[b], CAP);
        for (int e = t; e < m; e += 512)
            atomicAdd(&hist[bufD[(size_t)b * CAP + e] >> 17], 1);
        __syncthreads();
        int v = hist[t];
        int x = v;
#pragma unroll
        for (int o = 1; o < 64; o <<= 1) {
            int y = __shfl_up(x, o, 64);
            if ((t & 63) >= o) x += y;
        }
        if ((t & 63) == 63) wt[t >> 6] = x;
        __syncthreads();
        int base = 0;
        for (int w = 0; w < (t >> 6); ++w) base += wt[w];
        int excl = base + x - v;
        off[t] = excl;
        cnt2[t] = 0;
        __syncthreads();
        for (int e = t; e < m; e += 512) {
            unsigned w = bufD[(size_t)b * CAP + e];
            int dl = w >> 17;
            int s  = (int)(w & 0x1FFFFu);
            int pos = off[dl] + atomicAdd(&cnt2[dl], 1);
            stage[pos] = s;
        }
        __syncthreads();
        for (int e = t; e < m; e += 512)
            edgeC[(size_t)b * CAP + e] = (unsigned)stage[e];
        int node = (b << BSHIFT) + t;
        if (node < n_nodes)
            rpd[node] = (unsigned)(b * CAP + excl) |
                        ((unsigned)min(v, 2047) << 21);
    } else {
        int bb  = b - nb;              // 0 .. 4*nb-1
        int b2  = bb >> 2;             // source bucket
        int sub = bb & 3;              // which 128-node sub-range
        int lo  = sub << 7;            // local-id range [lo, lo+128)
        int node0 = (b2 << BSHIFT) + lo;
        if (t < 128) hist[t] = 0;
        __syncthreads();
        int m = min(curS[b2], CAP);
        for (int e = t; e < m; e += 512) {
            int v = (int)bufS[(size_t)b2 * CAP + e];
            int l = v - lo;
            if ((unsigned)l < 128u) atomicAdd(&hist[l], 1);
        }
        __syncthreads();
        int node = node0 + t;
        if (t < 128 && node < n_nodes)
            norm_out[node] = rsqrtf(fmaxf((float)hist[t], 1.0f));
        // fused scale: xp1[row] = fp16(feats[row] * norm_out[row])
        int m2 = min(128, n_nodes - node0);
        for (int i = t; i < m2 * 16; i += 512) {
            int row = i >> 4, c = i & 15;
            float no = rsqrtf(fmaxf((float)hist[row], 1.0f));
            float4 vv = ((const float4*)feats)[(size_t)(node0 + row) * 16 + c];
            uint2 o;
            o.x = (unsigned)f2h(vv.x * no) | ((unsigned)f2h(vv.y * no) << 16);
            o.y = (unsigned)f2h(vv.z * no) | ((unsigned)f2h(vv.w * no) << 16);
            xp1[(size_t)(node0 + row) * 16 + c] = o;
        }
    }
}

// ===========================================================================
// Fused gather + GEMV, TWO rows per wave (lanes 0-31 row A, 32-63 row B).
// R12: gather MLP widened 2 -> 4. Loads for edges g4,g4+4,g4+8,g4+12 issue
// unconditionally upfront (eld zero-padded -> inactive slots read row 0:
// always-valid, L2-hot); accumulation predicated on g4+k < dmax. Deg<=16
// (~89% of rows) now completes its gather in ONE issue batch instead of two
// serial rounds. Per-lane accumulation order unchanged (g4, g4+4, g4+8, ...)
// -> bit-identical results. (R8 pipeline / R9 LDS-W / R10 setprio all
// bounced off this serial-memory-round floor; this removes a round.)
// ===========================================================================
template <bool RELU, bool SCALE_OUT, bool OUT_HALF>
__global__ void __launch_bounds__(256)
gatherw_kernel(const unsigned int* __restrict__ xp,     // fp16 rows, 32 uints
               const unsigned int* __restrict__ rpd,
               const unsigned int* __restrict__ edgeC,
               const float* __restrict__ norm_out,
               const float* __restrict__ W,
               const float* __restrict__ bias,
               void* __restrict__ outv, int n_nodes) {
    __shared__ int eld[4][64];     // wave-private edge staging
    int lane   = threadIdx.x & 63;
    int wv     = threadIdx.x >> 6;
    int g      = lane >> 3, l8 = lane & 7;
    int half   = g >> 2;           // 0 -> row A, 1 -> row B
    int g4     = g & 3;            // group within my row (0..3)
    int base32 = lane & 32;
    int l32    = lane & 31;
    int wid  = (blockIdx.x * blockDim.x + threadIdx.x) >> 6;
    int nw   = (gridDim.x * blockDim.x) >> 6;

    // W pairs: wp[p] = (W[2p][lane], W[2p+1][lane]) as packed fp16
    h2 wp[32];
#pragma unroll
    for (int p = 0; p < 32; ++p) {
        h2 h;
        h.x = (_Float16)W[(2 * p) * D + lane];
        h.y = (_Float16)W[(2 * p + 1) * D + lane];
        wp[p] = h;
    }
    float bj = bias[lane];

    int npairs = (n_nodes + 1) >> 1;
    for (int pr = wid; pr < npairs; pr += nw) {
        int r0 = pr * 2;
        int rme = r0 + half;                    // row this half-wave gathers
        unsigned pk = (rme < n_nodes) ? rpd[rme] : 0u;
        int begme = (int)(pk & 0x1FFFFFu);
        int degme = (int)(pk >> 21);
        const unsigned int* el = edgeC + begme;

        int dmax = min(degme, 32);
        // one coalesced load per half; staged in LDS while fully converged
        eld[wv][lane] = (l32 < dmax) ? (int)el[l32] : 0;

        h2 a0 = (h2)0, a1 = (h2)0, a2 = (h2)0, a3 = (h2)0;
        // ---- batch 1: edges g4, g4+4, g4+8, g4+12 (covers dmax <= 16) ----
        {
            int s0 = eld[wv][base32 + g4];
            int s1 = eld[wv][base32 + g4 + 4];
            int s2 = eld[wv][base32 + g4 + 8];
            int s3 = eld[wv][base32 + g4 + 12];
            uint4 u0 = *(const uint4*)(xp + (size_t)s0 * 32 + l8 * 4);
            uint4 u1 = *(const uint4*)(xp + (size_t)s1 * 32 + l8 * 4);
            uint4 u2 = *(const uint4*)(xp + (size_t)s2 * 32 + l8 * 4);
            uint4 u3 = *(const uint4*)(xp + (size_t)s3 * 32 + l8 * 4);
            if (g4 < dmax)      { a0 += u2h(u0.x); a1 += u2h(u0.y); a2 += u2h(u0.z); a3 += u2h(u0.w); }
            if (g4 + 4 < dmax)  { a0 += u2h(u1.x); a1 += u2h(u1.y); a2 += u2h(u1.z); a3 += u2h(u1.w); }
            if (g4 + 8 < dmax)  { a0 += u2h(u2.x); a1 += u2h(u2.y); a2 += u2h(u2.z); a3 += u2h(u2.w); }
            if (g4 + 12 < dmax) { a0 += u2h(u3.x); a1 += u2h(u3.y); a2 += u2h(u3.z); a3 += u2h(u3.w); }
        }
        // ---- batch 2: edges g4+16 ... g4+28 (only when deg > 16) ----
        if (dmax > 16) {
            int s0 = eld[wv][base32 + g4 + 16];
            int s1 = eld[wv][base32 + g4 + 20];
            int s2 = eld[wv][base32 + g4 + 24];
            int s3 = eld[wv][base32 + g4 + 28];
            uint4 u0 = *(const uint4*)(xp + (size_t)s0 * 32 + l8 * 4);
            uint4 u1 = *(const uint4*)(xp + (size_t)s1 * 32 + l8 * 4);
            uint4 u2 = *(const uint4*)(xp + (size_t)s2 * 32 + l8 * 4);
            uint4 u3 = *(const uint4*)(xp + (size_t)s3 * 32 + l8 * 4);
            if (g4 + 16 < dmax) { a0 += u2h(u0.x); a1 += u2h(u0.y); a2 += u2h(u0.z); a3 += u2h(u0.w); }
            if (g4 + 20 < dmax) { a0 += u2h(u1.x); a1 += u2h(u1.y); a2 += u2h(u1.z); a3 += u2h(u1.w); }
            if (g4 + 24 < dmax) { a0 += u2h(u2.x); a1 += u2h(u2.y); a2 += u2h(u2.z); a3 += u2h(u2.w); }
            if (g4 + 28 < dmax) { a0 += u2h(u3.x); a1 += u2h(u3.y); a2 += u2h(u3.z); a3 += u2h(u3.w); }
        }
        for (int e2 = 32 + g4; e2 < degme; e2 += 4) {   // rare deg>32 tail
            int s0 = (int)el[e2];
            uint4 u = *(const uint4*)(xp + (size_t)s0 * 32 + l8 * 4);
            a0 += u2h(u.x); a1 += u2h(u.y); a2 += u2h(u.z); a3 += u2h(u.w);
        }
        // reduce the 4 groups of each half (lane bits 3,4) — both rows at once
#pragma unroll
        for (int off = 8; off < 32; off <<= 1) {
            a0 += u2h(__shfl_xor(h2u(a0), off, 64));
            a1 += u2h(__shfl_xor(h2u(a1), off, 64));
            a2 += u2h(__shfl_xor(h2u(a2), off, 64));
            a3 += u2h(__shfl_xor(h2u(a3), off, 64));
        }
        // row A slice sums in lanes 0-7, row B in lanes 32-39
        unsigned au[4] = {h2u(a0), h2u(a1), h2u(a2), h2u(a3)};

        // dual GEMV: pair p of row A in lane p>>2, row B in lane 32+(p>>2)
        float accA = 0.0f, accB = 0.0f;
#pragma unroll
        for (int p = 0; p < 32; ++p) {
            UH2 ta, tb;
            ta.u = __builtin_amdgcn_readlane(au[p & 3], p >> 2);
            tb.u = __builtin_amdgcn_readlane(au[p & 3], 32 + (p >> 2));
            accA = __builtin_amdgcn_fdot2(ta.h, wp[p], accA, false);
            accB = __builtin_amdgcn_fdot2(tb.h, wp[p], accB, false);
        }

        int degA = __builtin_amdgcn_readlane(degme, 0);
        int degB = __builtin_amdgcn_readlane(degme, 32);
        {
            float ni = rsqrtf(fmaxf((float)degA, 1.0f));
            float o  = fmaf(accA, ni, bj);
            if (RELU) o = fmaxf(o, 0.0f);
            if (SCALE_OUT) o *= norm_out[r0];
            if (OUT_HALF)
                ((unsigned short*)outv)[(size_t)r0 * D + lane] = f2h(o);
            else
                ((float*)outv)[(size_t)r0 * D + lane] = o;
        }
        if (r0 + 1 < n_nodes) {
            float ni = rsqrtf(fmaxf((float)degB, 1.0f));
            float o  = fmaf(accB, ni, bj);
            if (RELU) o = fmaxf(o, 0.0f);
            if (SCALE_OUT) o *= norm_out[r0 + 1];
            if (OUT_HALF)
                ((unsigned short*)outv)[(size_t)(r0 + 1) * D + lane] = f2h(o);
            else
                ((float*)outv)[(size_t)(r0 + 1) * D + lane] = o;
        }
    }
}

// ===========================================================================
// Minimal fallback (R1 atomic path) — only if workspace is tiny
// ===========================================================================
__global__ void degree_kernel(const int* __restrict__ src,
                              const int* __restrict__ dst,
                              float* __restrict__ deg_out,
                              float* __restrict__ deg_in, int n_edges) {
    int e = blockIdx.x * blockDim.x + threadIdx.x;
    if (e < n_edges) {
        atomicAdd(&deg_out[src[e]], 1.0f);
        atomicAdd(&deg_in[dst[e]], 1.0f);
    }
}
__global__ void norm_kernel(float* __restrict__ deg, int n) {
    int i = blockIdx.x * blockDim.x + threadIdx.x;
    if (i < n) deg[i] = rsqrtf(fmaxf(deg[i], 1.0f));
}
__global__ void spmm_kernel(const float* __restrict__ x,
                            const int* __restrict__ src,
                            const int* __restrict__ dst,
                            const float* __restrict__ norm_out,
                            float* __restrict__ agg, int n_edges) {
    int gid = blockIdx.x * blockDim.x + threadIdx.x;
    int e = gid >> 6, lane = threadIdx.x & 63;
    if (e < n_edges) {
        int s = src[e], d = dst[e];
        atomicAdd(&agg[(size_t)d * D + lane],
                  x[(size_t)s * D + lane] * norm_out[s]);
    }
}
template <bool RELU>
__global__ void gemm_kernel(const float* __restrict__ agg,
                            const float* __restrict__ norm_in,
                            const float* __restrict__ W,
                            const float* __restrict__ b,
                            float* __restrict__ out, int n_nodes) {
    __shared__ float Wl[D * D];
    for (int i = threadIdx.x; i < D * D; i += blockDim.x) Wl[i] = W[i];
    __syncthreads();
    int lane = threadIdx.x & 63, wave = threadIdx.x >> 6;
    int wpb = blockDim.x >> 6;
    float bj = b[lane];
    for (int row = blockIdx.x * wpb + wave; row < n_nodes;
         row += gridDim.x * wpb) {
        float aa = agg[(size_t)row * D + lane] * norm_in[row];
        float acc = bj;
#pragma unroll
        for (int k = 0; k < D; ++k)
            acc = fmaf(__shfl(aa, k, 64), Wl[k * D + lane], acc);
        if (RELU) acc = fmaxf(acc, 0.0f);
        out[(size_t)row * D + lane] = acc;
    }
}

// ===========================================================================
// Launch
// ===========================================================================
extern "C" void kernel_launch(void* const* d_in, const int* in_sizes, int n_in,
                              void* d_out, int out_size, void* d_ws, size_t ws_size,
                              hipStream_t stream) {
    const float* feats = (const float*)d_in[0];
    const int*   src   = (const int*)  d_in[1];
    const int*   dst   = (const int*)  d_in[2];
    const float* W1    = (const float*)d_in[3];
    const float* b1    = (const float*)d_in[4];
    const float* W2    = (const float*)d_in[5];
    const float* b2    = (const float*)d_in[6];
    float*       out   = (float*)d_out;

    const int n_nodes = in_sizes[0] / D;   // 100000
    const int n_edges = in_sizes[1];       // 1200000
    const size_t nd = (size_t)n_nodes * D;
    const int nb = (n_nodes + BSIZE - 1) >> BSHIFT;

    // Layout: [bufD nb*CAP u32 (reused as edgeC)][bufS nb*CAP u16]
    //         [xp1 half N*D][xa half N*D][rpd N][norm_out N][curD 256][curS 256]
    size_t bufD_sz = (size_t)nb * CAP * 4;
    size_t bufS_sz = (size_t)nb * CAP * 2;
    size_t need = bufD_sz + bufS_sz + nd * 2 * 2 + (size_t)n_nodes * 8 + 2048;

    if (ws_size >= need && nb <= NBMAX && (size_t)nb * CAP < (1u << 21)) {
        char* base = (char*)d_ws;
        unsigned int*   bufD = (unsigned int*)base;
        unsigned short* bufS = (unsigned short*)(base + bufD_sz);
        unsigned int*   xp1  = (unsigned int*)(base + bufD_sz + bufS_sz);
        unsigned int*   xa   = (unsigned int*)((char*)xp1 + nd * 2);
        unsigned int*   rpd  = (unsigned int*)((char*)xa + nd * 2);
        float* norm_out = (float*)(rpd + n_nodes);
        int*   curD     = (int*)(norm_out + n_nodes);
        int*   curS     = curD + 256;

        hipMemsetAsync(curD, 0, 2048, stream);
        binA_kernel<<<512, 512, 0, stream>>>(src, dst, curD, curS, bufD, bufS,
                                             n_edges);
        binBC_kernel<<<5 * nb, 512, 0, stream>>>(bufD, bufD, bufS, curD, curS,
                                                 rpd, norm_out,
                                                 feats, (uint2*)xp1,
                                                 n_nodes, nb);

        // Layer 1: xp1 -> xa (fp16, pre-scaled by norm_out for next layer)
        gatherw_kernel<true, true, true><<<6400, 256, 0, stream>>>(
            xp1, rpd, bufD, norm_out, W1, b1, xa, n_nodes);
        // Layer 2: xa -> final fp32 out
        gatherw_kernel<false, false, false><<<6400, 256, 0, stream>>>(
            xa, rpd, bufD, norm_out, W2, b2, out, n_nodes);
        return;
    }

    // ---------------- fallback: R1 atomic path ----------------
    float* deg_out = (float*)d_ws;
    float* deg_in  = deg_out + n_nodes;
    float* agg     = deg_in + n_nodes;
    float* x       = out;

    hipMemsetAsync(d_ws, 0, (2 * (size_t)n_nodes + nd) * sizeof(float), stream);
    degree_kernel<<<(n_edges + 255) / 256, 256, 0, stream>>>(src, dst, deg_out,
                                                             deg_in, n_edges);
    norm_kernel<<<(2 * n_nodes + 255) / 256, 256, 0, stream>>>(deg_out,
                                                               2 * n_nodes);
    {
        long long threads = (long long)n_edges * 64;
        int blocks = (int)((threads + 255) / 256);
        spmm_kernel<<<blocks, 256, 0, stream>>>(feats, src, dst, deg_out, agg,
                                                n_edges);
    }
    gemm_kernel<true><<<(n_nodes + 3) / 4, 256, 0, stream>>>(agg, deg_in, W1,
                                                             b1, x, n_nodes);
    hipMemsetAsync(agg, 0, nd * sizeof(float), stream);
    {
        long long threads = (long long)n_edges * 64;
        int blocks = (int)((threads + 255) / 256);
        spmm_kernel<<<blocks, 256, 0, stream>>>(x, src, dst, deg_out, agg,
                                                n_edges);
    }
    gemm_kernel<false><<<(n_nodes + 3) / 4, 256, 0, stream>>>(agg, deg_in, W2,
                                                              b2, out, n_nodes);
}